// Round 9
// baseline (591.889 us; speedup 1.0000x reference)
//
#include <hip/hip_runtime.h>

// B=4,H=8,N=2048,DV=64. BH=32.
// P_d = stable argsort of v[:,d] (per bh), Q_d = inverse perm (rank), vs_d = sorted col.
// out[r,d] = vs_d[ Q_{(d+1)%64}[r] ]
// attn[r,:] = one_hot( P_0[ Q_1[r] ] )
//
// ws: Q ushort[32*64*2048] (8MB) | vs float[32*64*2048] (16MB) |
//     P0 ushort[32*2048] | spike uint[32*2048] | outT float (16MB @ ws+32MB)
//
// Measured lessons (R4-R8):
//  - NT stores cost ~1.4x on the 536MB attn stream. BANNED.
//  - fused plain-store one-hot already runs at fill speed (~6.2 TB/s).
//  - rank internals (atomics, vectorization) don't move total. Kernel COUNT
//    and overlap are the remaining lever:
//    * v_transpose dropped: rank gathers v columns directly; the 64 same-bh
//      blocks reuse each 64B line (16 d's/line) via L2. 16MB HBM vs 48MB.
//    * out_transpose fused into attn kernel (outT lives in ws, no aliasing),
//      hiding the 16MB transpose under the 536MB write-bound attn stream.

#define SORT_N 2048
#define NBH 32
#define NDV 64
#define SLOT(i)  ((i) + ((i) >> 3))   // u64 pad: breaks 64B-stride bank aliasing
#define HS(i)    ((i) + ((i) >> 5))   // u32 pad for the histogram array

// ---------------- Kernel 1: exact bucket-rank per column --------------------
// One WG per (bh,d) column. Thread t owns idx = 4t..4t+3 and 1024+4t..+3.
// Reads v[bh][idx][d] directly (stride-256B gather; L2-shared across d).
__global__ __launch_bounds__(256) void rank_kernel(
    const float* __restrict__ v, unsigned short* __restrict__ Q,
    float* __restrict__ vs, unsigned short* __restrict__ P0) {
  const int col = blockIdx.x;        // bh*64 + d
  const int bh  = col >> 6;
  const int d   = col & 63;
  const float* vcol = v + (((size_t)bh << 11) << 6) + d;   // element r at vcol[r<<6]

  __shared__ unsigned base[2176];                       // HS-padded 2049 (sentinel)
  __shared__ unsigned long long bkt[SORT_N + 256];      // SLOT-padded scatter
  __shared__ float vsorted[SORT_N];
  __shared__ unsigned wsum[4];

  const int t = threadIdx.x;

  float x[8]; unsigned key[8]; int bk[8]; unsigned off[8];
#pragma unroll
  for (int e = 0; e < 8; ++e) {
    const unsigned idx = (unsigned)((t << 2) + ((e >> 2) << 10) + (e & 3));
    float f = vcol[(size_t)idx << 6];                   // strided gather
    x[e] = f;
    unsigned u = __float_as_uint(f);
    key[e] = (u & 0x80000000u) ? ~u : (u | 0x80000000u);  // order-preserving
    float tb = fmaf(f, 372.3636f, 1024.0f);             // monotone bucket map
    tb = fminf(fmaxf(tb, 0.0f), 2047.0f);
    bk[e] = (int)tb;                                    // trunc==floor (tb>=0)
  }

  for (int i = t; i < 2176; i += 256) base[i] = 0;
  __syncthreads();

  // single atomic pass: count AND capture within-bucket offset
#pragma unroll
  for (int e = 0; e < 8; ++e) off[e] = atomicAdd(&base[HS(bk[e])], 1u);
  __syncthreads();

  // block exclusive scan over the 2048 bins (thread t owns bins 8t..8t+7)
  unsigned c[8];
#pragma unroll
  for (int e = 0; e < 8; ++e) c[e] = base[HS((t << 3) + e)];
  unsigned s = 0;
#pragma unroll
  for (int e = 0; e < 8; ++e) s += c[e];
  unsigned incl = s;
  for (int o = 1; o < 64; o <<= 1) {
    unsigned tmp = __shfl_up(incl, o);
    if ((t & 63) >= o) incl += tmp;
  }
  const int w = t >> 6;
  if ((t & 63) == 63) wsum[w] = incl;
  __syncthreads();
  unsigned run = incl - s;                              // exclusive within wave
  for (int i = 0; i < w; ++i) run += wsum[i];           // + earlier waves
#pragma unroll
  for (int e = 0; e < 8; ++e) {                         // own slots: no race
    unsigned cc = c[e];
    base[HS((t << 3) + e)] = run;                       // exclusive bucket base
    run += cc;
  }
  if (t == 0) base[HS(2048)] = SORT_N;                  // sentinel end
  __syncthreads();

  // scatter (key<<32|idx) at excl_base + captured offset (no atomics)
#pragma unroll
  for (int e = 0; e < 8; ++e) {
    unsigned idx = (unsigned)((t << 2) + ((e >> 2) << 10) + (e & 3));
    unsigned long long me = ((unsigned long long)key[e] << 32) | idx;
    bkt[SLOT(base[HS(bk[e])] + off[e])] = me;
  }
  __syncthreads();

  // exact rank = bucket start + #{strictly smaller (key,idx) in bucket}
  unsigned short* Qcol = Q + ((size_t)col << 11);
  float* vscol = vs + ((size_t)col << 11);
  unsigned short qr[8];
#pragma unroll
  for (int e = 0; e < 8; ++e) {
    unsigned idx = (unsigned)((t << 2) + ((e >> 2) << 10) + (e & 3));
    const int b = bk[e];
    unsigned start = base[HS(b)];
    unsigned end   = base[HS(b + 1)];
    unsigned long long me = ((unsigned long long)key[e] << 32) | idx;
    unsigned r = start;
    for (unsigned p = start; p < end; ++p)
      r += (bkt[SLOT(p)] < me) ? 1u : 0u;
    qr[e] = (unsigned short)r;
    vsorted[r] = x[e];                                  // LDS scatter
    if (d == 0) P0[((size_t)bh << 11) + r] = (unsigned short)idx;
  }
  {                                                     // 8B coalesced Q writes
    ushort4 qlo = {qr[0], qr[1], qr[2], qr[3]};
    ushort4 qhi = {qr[4], qr[5], qr[6], qr[7]};
    *(ushort4*)(Qcol + (t << 2)) = qlo;
    *(ushort4*)(Qcol + (t << 2) + 1024) = qhi;
  }
  __syncthreads();
  {                                                     // 16B coalesced vs write
    float4* vs4 = (float4*)vscol;
    const float4* vso4 = (const float4*)vsorted;
#pragma unroll
    for (int h = 0; h < 2; ++h) vs4[t + (h << 8)] = vso4[t + (h << 8)];
  }
}

// ------- Kernel 2: outT[(bh,d)][r] = vs_d[Q_{d+1}[r]]  (all coalesced) ------
// d==0 blocks additionally emit spike[bh*2048+r] = P0[Q_1[r]] (they hold Q_1).
__global__ __launch_bounds__(256) void out_colT_kernel(
    const unsigned short* __restrict__ Q, const float* __restrict__ vs,
    const unsigned short* __restrict__ P0, float* __restrict__ outT,
    unsigned* __restrict__ spike) {
  const int b  = blockIdx.x;         // bh*64 + d
  const int bh = b >> 6;
  const int d  = b & 63;
  const int dn = (d + 1) & 63;
  const int t  = threadIdx.x;

  __shared__ float col[SORT_N];      // 8 KiB
  __shared__ unsigned short P0s[SORT_N];  // 4 KiB (used only by d==0 blocks)
  const float4* vcol4 = (const float4*)(vs + ((size_t)b << 11));
  float4* col4 = (float4*)col;
  for (int r4 = t; r4 < 512; r4 += 256) col4[r4] = vcol4[r4];   // 16B coalesced
  if (d == 0)
    for (int r = t; r < SORT_N; r += 256) P0s[r] = P0[((size_t)bh << 11) + r];
  __syncthreads();

  const ushort4* Qv = (const ushort4*)(Q + ((size_t)((bh << 6) + dn) << 11));
  float4* ov = (float4*)(outT + ((size_t)b << 11));
  for (int r4 = t; r4 < 512; r4 += 256) {
    ushort4 qq = Qv[r4];             // 8B coalesced ushort read
    float4 val;
    val.x = col[qq.x]; val.y = col[qq.y];
    val.z = col[qq.z]; val.w = col[qq.w];
    ov[r4] = val;                    // 16B coalesced write
    if (d == 0) {                    // spike side-product: P0[Q_1[r]]
      int r = r4 << 2;
      unsigned base_i = ((unsigned)bh << 11) + (unsigned)r;
      spike[base_i + 0] = P0s[qq.x];
      spike[base_i + 1] = P0s[qq.y];
      spike[base_i + 2] = P0s[qq.z];
      spike[base_i + 3] = P0s[qq.w];
    }
  }
}

// ---- Kernel 3 (fused): blocks 0..1023 = out transpose, rest = attn rows ----
__global__ __launch_bounds__(256) void finish_kernel(
    const float* __restrict__ outT, float* __restrict__ out,
    const unsigned* __restrict__ spike, float* __restrict__ attn) {
  __shared__ float tile[64][65];     // +1 pad breaks bank conflicts
  const int t = threadIdx.x;
  if (blockIdx.x < NBH * 32) {
    // ---- out[r][d] = outT[d][r], 64x64 LDS tile ----
    const int blk = blockIdx.x;      // bh*32 + rtile
    const int bh = blk >> 5;
    const int r0 = (blk & 31) << 6;  // 64-row tile
    const int tx = t & 63;
    const int ty = t >> 6;           // 0..3
    for (int i = ty; i < 64; i += 4) // read outT[d=i][r0+tx] coalesced
      tile[i][tx] = outT[(((size_t)(bh << 6) + i) << 11) + r0 + tx];
    __syncthreads();
    for (int i = ty; i < 64; i += 4) // write out[r0+i][d=tx] coalesced
      out[(((size_t)(bh << 11) + r0 + i) << 6) + tx] = tile[tx][i];
  } else {
    // ---- attn row one-hot (R1-proven shape; plain stores) ----
    const int row = blockIdx.x - NBH * 32;   // bh*2048 + r
    const int idx = (int)spike[row];         // uniform scalar load
    float4* rowp = (float4*)(attn + ((size_t)row << 11));
#pragma unroll
    for (int it = 0; it < 2; ++it) {
      int f4 = t + (it << 8);
      int basei = f4 << 2;
      float4 val;
      val.x = (basei + 0 == idx) ? 1.0f : 0.0f;
      val.y = (basei + 1 == idx) ? 1.0f : 0.0f;
      val.z = (basei + 2 == idx) ? 1.0f : 0.0f;
      val.w = (basei + 3 == idx) ? 1.0f : 0.0f;
      rowp[f4] = val;
    }
  }
}

// ---- Fallback kernels (ws too small for outT): R8-proven serial path -------
__global__ __launch_bounds__(256) void out_transpose_kernel(
    const float* __restrict__ outT, float* __restrict__ out) {
  __shared__ float tile[64][65];
  const int blk = blockIdx.x;
  const int bh = blk >> 5;
  const int r0 = (blk & 31) << 6;
  const int tx = threadIdx.x & 63;
  const int ty = threadIdx.x >> 6;
  for (int i = ty; i < 64; i += 4)
    tile[i][tx] = outT[(((size_t)(bh << 6) + i) << 11) + r0 + tx];
  __syncthreads();
  for (int i = ty; i < 64; i += 4)
    out[(((size_t)(bh << 11) + r0 + i) << 6) + tx] = tile[tx][i];
}

__global__ __launch_bounds__(256) void attn_kernel(
    const unsigned* __restrict__ spike, float* __restrict__ attn) {
  const int row = blockIdx.x;
  const int idx = (int)spike[row];
  float4* rowp = (float4*)(attn + ((size_t)row << 11));
  const int t = threadIdx.x;
#pragma unroll
  for (int it = 0; it < 2; ++it) {
    int f4 = t + (it << 8);
    int basei = f4 << 2;
    float4 val;
    val.x = (basei + 0 == idx) ? 1.0f : 0.0f;
    val.y = (basei + 1 == idx) ? 1.0f : 0.0f;
    val.z = (basei + 2 == idx) ? 1.0f : 0.0f;
    val.w = (basei + 3 == idx) ? 1.0f : 0.0f;
    rowp[f4] = val;
  }
}

extern "C" void kernel_launch(void* const* d_in, const int* in_sizes, int n_in,
                              void* d_out, int out_size, void* d_ws, size_t ws_size,
                              hipStream_t stream) {
  const float* v = (const float*)d_in[2];     // q,k unused by reference
  float* out  = (float*)d_out;
  float* attn = out + (size_t)NBH * SORT_N * NDV;

  unsigned short* Q  = (unsigned short*)d_ws;                             // 8 MiB
  float* vs          = (float*)((char*)d_ws + (size_t)8 * 1024 * 1024);   // 16 MiB
  unsigned short* P0 = (unsigned short*)((char*)d_ws + (size_t)24 * 1024 * 1024);
  unsigned* spike    = (unsigned*)((char*)d_ws + (size_t)24 * 1024 * 1024 + 256 * 1024);

  const size_t outT_need = (size_t)48 * 1024 * 1024;    // 32MB used + 16MB outT
  if (ws_size >= outT_need) {
    float* outT = (float*)((char*)d_ws + (size_t)32 * 1024 * 1024);
    rank_kernel<<<NBH * NDV, 256, 0, stream>>>(v, Q, vs, P0);
    out_colT_kernel<<<NBH * NDV, 256, 0, stream>>>(Q, vs, P0, outT, spike);
    finish_kernel<<<NBH * 32 + NBH * SORT_N, 256, 0, stream>>>(outT, out, spike, attn);
  } else {
    float* outT = attn;                                 // aliased, serial path
    rank_kernel<<<NBH * NDV, 256, 0, stream>>>(v, Q, vs, P0);
    out_colT_kernel<<<NBH * NDV, 256, 0, stream>>>(Q, vs, P0, outT, spike);
    out_transpose_kernel<<<NBH * 32, 256, 0, stream>>>(outT, out);
    attn_kernel<<<NBH * SORT_N, 256, 0, stream>>>(spike, attn);
  }
}